// Round 4
// baseline (76.026 us; speedup 1.0000x reference)
//
#include <hip/hip_runtime.h>

// TripletLoss semi-hard, B=512, D=256, fp32.
// K1 pd_gemm: 256 blocks x 256 thr, one 32x32 pd tile per block.
//   K=256 split 4 ways across the 4 waves (wave w: k in [64w,64w+64)).
//   Per-lane 4x4 outputs (rows a+8i, cols b+8j; a=lane>>3, b=lane&7) ->
//   all K-loop LDS reads are 8-lane broadcasts (conflict-free), and LDS
//   instrs/CU halve vs 2x2 (512 ds_read_b128 ~ 2.6 us) while FMA spreads
//   over all 4 SIMDs (1024 v_fma/wave ~ 0.85 us). Partials combined via
//   LDS ds_add_f32; epilogue pd = max(sq_r+sq_c-2dot,0), diag zeroed,
//   coalesced float4 stores.
// K2 mining: 128 blocks x 256 thr, one wave per anchor; pd row + labels in
//   registers; ballot over positives + shuffle broadcast + butterfly min;
//   device atomicAdd partials, last block (ticket) finalizes loss.

#define BN 512
#define DF4 64

__device__ inline float wave_max64(float v){
  #pragma unroll
  for (int o = 32; o > 0; o >>= 1) v = fmaxf(v, __shfl_xor(v, o));
  return v;
}
__device__ inline float wave_min64(float v){
  #pragma unroll
  for (int o = 32; o > 0; o >>= 1) v = fminf(v, __shfl_xor(v, o));
  return v;
}
__device__ inline float dot4(float4 a, float4 b){
  return a.x*b.x + a.y*b.y + a.z*b.z + a.w*b.w;
}

__global__ __launch_bounds__(256) void pd_gemm(
    const float* __restrict__ emb, float* __restrict__ pd, float* __restrict__ acc)
{
  __shared__ float As[32][260];   // stride 260 floats: K-loop reads broadcast
  __shared__ float Bs[32][260];
  __shared__ float pdbuf[32][36]; // dot-product combine buffer (2-way max banks)
  __shared__ float sqA[32], sqB[32];

  const int t    = threadIdx.x;
  const int lane = t & 63, wid = t >> 6;
  const int bi = blockIdx.x & 15, bj = blockIdx.x >> 4;
  const int R0 = bi * 32, C0 = bj * 32;
  const float4* ef4 = reinterpret_cast<const float4*>(emb);

  if (blockIdx.x == 0 && t == 0){ acc[0] = 0.f; acc[1] = 0.f; ((int*)acc)[2] = 0; }

  // zero the combine buffer (covered by the staging barrier)
  for (int idx = t; idx < 32 * 36; idx += 256) ((float*)pdbuf)[idx] = 0.f;

  // stage both 32x256 tiles, coalesced 1KB/instr
  #pragma unroll
  for (int j = 0; j < 8; ++j){
    int idx = t + j * 256;
    int r = idx >> 6, c = idx & 63;
    *(float4*)&As[r][c * 4] = ef4[(R0 + r) * DF4 + c];
    *(float4*)&Bs[r][c * 4] = ef4[(C0 + r) * DF4 + c];
  }
  // sq norms straight from global (L2-hot), overlaps staging
  {
    int half = t >> 7, u = t & 127;
    int r = u >> 2, part = u & 3;
    int base = ((half ? C0 : R0) + r) * DF4 + part * 16;
    float s = 0.f;
    #pragma unroll
    for (int i = 0; i < 16; ++i){
      float4 v = ef4[base + i];
      s += v.x*v.x + v.y*v.y + v.z*v.z + v.w*v.w;
    }
    s += __shfl_xor(s, 1); s += __shfl_xor(s, 2);
    if (part == 0){ if (half) sqB[r] = s; else sqA[r] = s; }
  }
  __syncthreads();

  // K-split across waves: wave wid handles k in [wid*64, wid*64+64)
  const int a = lane >> 3, b = lane & 7;   // row-group / col-group
  float acc4[4][4];
  #pragma unroll
  for (int i = 0; i < 4; ++i)
    #pragma unroll
    for (int j = 0; j < 4; ++j) acc4[i][j] = 0.f;

  const int kb = wid * 64;
  #pragma unroll 4
  for (int q = 0; q < 16; ++q){
    const int kq = kb + q * 4;
    float4 A0 = *(const float4*)&As[a     ][kq];
    float4 A1 = *(const float4*)&As[a +  8][kq];
    float4 A2 = *(const float4*)&As[a + 16][kq];
    float4 A3 = *(const float4*)&As[a + 24][kq];
    float4 B0 = *(const float4*)&Bs[b     ][kq];
    float4 B1 = *(const float4*)&Bs[b +  8][kq];
    float4 B2 = *(const float4*)&Bs[b + 16][kq];
    float4 B3 = *(const float4*)&Bs[b + 24][kq];
    acc4[0][0] += dot4(A0,B0); acc4[0][1] += dot4(A0,B1);
    acc4[0][2] += dot4(A0,B2); acc4[0][3] += dot4(A0,B3);
    acc4[1][0] += dot4(A1,B0); acc4[1][1] += dot4(A1,B1);
    acc4[1][2] += dot4(A1,B2); acc4[1][3] += dot4(A1,B3);
    acc4[2][0] += dot4(A2,B0); acc4[2][1] += dot4(A2,B1);
    acc4[2][2] += dot4(A2,B2); acc4[2][3] += dot4(A2,B3);
    acc4[3][0] += dot4(A3,B0); acc4[3][1] += dot4(A3,B1);
    acc4[3][2] += dot4(A3,B2); acc4[3][3] += dot4(A3,B3);
  }

  // combine the 4 waves' K-partials (LDS f32 atomics, <=2-way banks)
  #pragma unroll
  for (int i = 0; i < 4; ++i)
    #pragma unroll
    for (int j = 0; j < 4; ++j)
      atomicAdd(&pdbuf[a + 8 * i][b + 8 * j], acc4[i][j]);
  __syncthreads();

  // epilogue: 4 outputs/thread, coalesced float4 store
  {
    int r = t >> 3, cb = (t & 7) * 4;
    float4 d = *(const float4*)&pdbuf[r][cb];
    float sr = sqA[r];
    float4 o;
    o.x = fmaxf(sr + sqB[cb    ] - 2.f * d.x, 0.f);
    o.y = fmaxf(sr + sqB[cb + 1] - 2.f * d.y, 0.f);
    o.z = fmaxf(sr + sqB[cb + 2] - 2.f * d.z, 0.f);
    o.w = fmaxf(sr + sqB[cb + 3] - 2.f * d.w, 0.f);
    if (bi == bj){                     // zero the diagonal (reference semantics)
      if (r == cb    ) o.x = 0.f;
      if (r == cb + 1) o.y = 0.f;
      if (r == cb + 2) o.z = 0.f;
      if (r == cb + 3) o.w = 0.f;
    }
    *(float4*)&pd[(size_t)(R0 + r) * BN + C0 + cb] = o;
  }
}

__global__ __launch_bounds__(256) void mining(
    const float* __restrict__ pd, const int* __restrict__ labels,
    float* __restrict__ acc, float* __restrict__ out)
{
  __shared__ float wls[4], wcs[4];
  const int t = threadIdx.x, lane = t & 63, wid = t >> 6;
  const int j  = blockIdx.x * 4 + wid;          // one anchor per wave
  const int lj = labels[j];

  const float4* prow = reinterpret_cast<const float4*>(pd + (size_t)j * BN);
  const int4*   lrow = reinterpret_cast<const int4*>(labels);
  float4 p0 = prow[lane * 2], p1 = prow[lane * 2 + 1];
  int4   l0 = lrow[lane * 2], l1 = lrow[lane * 2 + 1];
  float pk[8] = {p0.x, p0.y, p0.z, p0.w, p1.x, p1.y, p1.z, p1.w};
  int   lk[8] = {l0.x, l0.y, l0.z, l0.w, l1.x, l1.y, l1.z, l1.w};
  const int kbase = lane * 8;

  // negatives_inside: max over adj_not (rowmin filler == 0 since diag is 0)
  float ninside = 0.f;
  #pragma unroll
  for (int m = 0; m < 8; ++m)
    if (lk[m] != lj) ninside = fmaxf(ninside, pk[m]);
  ninside = wave_max64(ninside);

  float lsum = 0.f; int pcnt = 0;
  #pragma unroll
  for (int m = 0; m < 8; ++m){
    unsigned long long bal = __ballot(lk[m] == lj && (kbase + m) != j);
    while (bal){
      int L = (int)__ffsll((unsigned long long)bal) - 1;
      bal &= bal - 1;
      float tiv = __shfl(pk[m], L);             // pd[j][i], broadcast
      float vmin = 3.402823466e38f;
      #pragma unroll
      for (int mm = 0; mm < 8; ++mm)
        if (lk[mm] != lj && pk[mm] > tiv) vmin = fminf(vmin, pk[mm]);
      vmin = wave_min64(vmin);
      float semi = (vmin < 3.0e38f) ? vmin : ninside;  // mask_final fallback
      lsum += fmaxf(1.0f + tiv - semi, 0.f);
      ++pcnt;                                   // identical on all lanes
    }
  }

  if (lane == 0){ wls[wid] = lsum; wcs[wid] = (float)pcnt; }
  __syncthreads();
  if (t == 0){
    float bl = wls[0] + wls[1] + wls[2] + wls[3];
    float bc = wcs[0] + wcs[1] + wcs[2] + wcs[3];
    atomicAdd(&acc[0], bl);
    atomicAdd(&acc[1], bc);
    __threadfence();
    int tk = atomicAdd((int*)acc + 2, 1);
    if (tk == 127){                             // last block finalizes
      __threadfence();
      float tot = atomicAdd(&acc[0], 0.f);      // device-scope coherent read
      float cnt = atomicAdd(&acc[1], 0.f);
      out[0] = tot / cnt;
    }
  }
}

extern "C" void kernel_launch(void* const* d_in, const int* in_sizes, int n_in,
                              void* d_out, int out_size, void* d_ws, size_t ws_size,
                              hipStream_t stream) {
  const float* emb    = (const float*)d_in[0];
  const int*   labels = (const int*)d_in[1];
  float* out = (float*)d_out;
  float* pdw = (float*)d_ws;                 // [512*512] pd matrix
  float* acc = pdw + BN * BN;                // [0]=loss, [1]=count, [2]=ticket
  pd_gemm<<<256, 256, 0, stream>>>(emb, pdw, acc);
  mining<<<128, 256, 0, stream>>>(pdw, labels, acc, out);
}